// Round 7
// baseline (105.675 us; speedup 1.0000x reference)
//
#include <hip/hip_runtime.h>
#include <hip/hip_bf16.h>

// ---------------------------------------------------------------------------
// KroneNet fused kernel v14 for MI355X (gfx950)
// out[i][j] = softmax_j( s_a[i] * t_j[i] )
// History: v8 40.9us / v9 ~36.5us / v10 FAILED (red4 mirror) / v11 50us
// (spill) / v12 45.5us (dbuf structure stall) / v13 ~36us = v9 structure +
// verified cuts (red4 rotations, log2 softmax, W3T, compact store).
// v14: layer-1 moved from VALU to MFMA (the pipe is ~80% idle):
//   - W1 staged as pre-built A-fragments (W1F) with a row PERMUTATION chosen
//     so layer-1's MFMA D-layout == layer-2's A-frag layout:
//     tile t'=2s+p holds rows n1 = s*32 + quad*8 + p*4 + r  (r = D reg idx)
//     -> per s-step: 2 A-frag ds_read_b128 + 4 MFMA + 8 max + 4 pack
//     replaces 8 ds_read_b128 + 32 fmaf + 16 max + 8 pack.
//   - full precision via hi/lo bf16 splits in the K=32 budget:
//     A j0..7 = whi0,whi1,wlo0,wlo1,whi0,whi1,b1hi,b1lo
//     B j0..7 = xhi0,xhi1,xhi0,xhi1,xlo0,xlo1,1,1
//     sum = whi*xhi + wlo*xhi + whi*xlo + b1  (error ~2^-15, << bf16-h round)
//   - everything else byte-identical to v13 (layer-2, epilogues, red4,
//     softmax, store, phase structure) -- one variable changed.
// ---------------------------------------------------------------------------

#define BTOT 262144
#define NBLK (BTOT / 512)   // 512 blocks x 512 samples (8 waves x 64)

typedef __attribute__((ext_vector_type(4))) float floatx4;
typedef __attribute__((ext_vector_type(8))) short bf16x8;
typedef __attribute__((ext_vector_type(4))) int  intx4;

// LDS layout (bytes), one W2 path resident at a time
#define OFF_W2    0          // 4 ksteps * 8 ntiles * 64 lanes * 16B = 32768
#define OFF_W1FA  32768      // 8 tiles * 64 lanes * 16B A-frags    = 8192
#define OFF_W1FB  40960      // 8192
#define OFF_B2A   49152      // 128 * float                         = 512
#define OFF_B2B   49664      // 512
#define OFF_W3A   50176      // 128 * float                         = 512
#define OFF_W3T   50688      // 128 * float4 (w3b transposed [n][j])= 2048
#define OFF_SA    52736      // 512 * float (s_a * log2e)           = 2048
#define LDS_TOTAL 54784

// pack two fp32 -> one dword of two bf16 (lo16=bf16(a), hi16=bf16(b)), RNE
static __device__ __forceinline__ int pack2bf(float lo, float hi) {
    int r;
    asm("v_cvt_pk_bf16_f32 %0, %1, %2" : "=v"(r) : "v"(lo), "v"(hi));
    return r;
}

// DPP-fused butterfly add: v += lanes-permuted(v), 1 VALU inst per stage.
// 0xB1=quad_perm xor1, 0x4E=quad_perm xor2,
// 0x124=row_ror:4, 0x128=row_ror:8 (true rotations within the 16-lane row)
template <int CTRL>
static __device__ __forceinline__ float dppadd(float v) {
    int t = __builtin_amdgcn_update_dpp(0, __builtin_bit_cast(int, v),
                                        CTRL, 0xF, 0xF, true);
    return v + __builtin_bit_cast(float, t);
}

// Multiplexed 4-value reduce over 16 cols: 12 insts; lane c ends with the
// 16-col sum of a_{c&3} (cols 0..3 hold a0..a3 directly). Stages 3,4 use
// row_ror rotations -- the transversal {c,c+4,c+8,c+12} preserves c&3
// (mirrors are xor7/xor15 and would mix samples: the v10 bug).
static __device__ __forceinline__ float red4(float a0, float a1, float a2,
                                             float a3, int col) {
    float s0 = dppadd<0xB1>(a0), s1 = dppadd<0xB1>(a1);
    float s2 = dppadd<0xB1>(a2), s3 = dppadd<0xB1>(a3);
    float u0 = (col & 1) ? s1 : s0;
    float u1 = (col & 1) ? s3 : s2;
    float v0 = dppadd<0x4E>(u0), v1 = dppadd<0x4E>(u1);
    float w  = (col & 2) ? v1 : v0;
    w = dppadd<0x124>(w);   // += m[c+4]
    w = dppadd<0x128>(w);   // += m[c+8] + m[c+12]
    return w;
}

// Pack one path's W2 into LDS (512 threads, 8 iters).
// W2 mapping (verified v5-v13): k=4*k4: dest = (s*8+t)*1024 + l*16 + (k&7)*2,
// s=k>>5, l=((k&31)>>3)*16+(n&15), t=n>>4. Lane remap keeps write
// conflicts <=4-way.
static __device__ __forceinline__ void pack_w2(
        unsigned char* dst, int tid, const float* __restrict__ w2) {
    const float4* w2p = (const float4*)w2;
    #pragma unroll
    for (int i = 0; i < 8; ++i) {
        int n  = (tid & 15) | (i << 4);
        int k4 = tid >> 4;
        float4 f = w2p[n * 32 + k4];
        int k = k4 * 4;
        int s = k >> 5;
        int j0 = k & 7;               // 0 or 4
        int l = ((k & 31) >> 3) * 16 + (n & 15);
        int2 pkd;
        pkd.x = pack2bf(f.x, f.y);
        pkd.y = pack2bf(f.z, f.w);
        *(int2*)(dst + (s * 8 + (n >> 4)) * 1024 + l * 16 + j0 * 2) = pkd;
    }
}

// Stage one path's W1+b1 as layer-1 MFMA A-fragments, one entry per thread.
// Entry (tile tp, lane l): A[row = l&15][k = (l>>4)*8 + j]; only k=0..7
// nonzero -> lanes l>=16 store zeros. Row permutation:
//   n1 = (tp>>1)*32 + (row>>2)*8 + (tp&1)*4 + (row&3)
// so layer-1 D reg r at lane (quad,col) == layer-2 A-frag j = (tp&1)*4+r.
// dwords: {pack(whi0,whi1), pack(wlo0,wlo1), pack(whi0,whi1), pack(b1hi,b1lo)}
static __device__ __forceinline__ void stage_w1f(
        unsigned char* smem, int off, int tid,
        const float* __restrict__ w1, const float* __restrict__ b1) {
    int tp = tid >> 6, l = tid & 63;
    intx4 e = (intx4){0, 0, 0, 0};
    if (l < 16) {
        int n1 = (tp >> 1) * 32 + (l >> 2) * 8 + (tp & 1) * 4 + (l & 3);
        float w0 = w1[2 * n1], w1v = w1[2 * n1 + 1], bb = b1[n1];
        int dhi = pack2bf(w0, w1v);
        float w0r = __builtin_bit_cast(float, dhi << 16);
        float w1r = __builtin_bit_cast(float, dhi & 0xffff0000);
        int dlo = pack2bf(w0 - w0r, w1v - w1r);
        int bh  = pack2bf(bb, 0.f);
        float bbr = __builtin_bit_cast(float, bh << 16);
        int dbias = pack2bf(bb, bb - bbr);
        e = (intx4){dhi, dlo, dhi, dbias};
    }
    ((intx4*)(smem + off))[tid] = e;
}

// One chunk's GEMM: acc = W2 . relu(W1.x+b1) + b2 (acc pre-init with b2).
// acc layout: (t, mt, r) -> sample mt*16+quad*4+r, n = t*16+col.
// Layer-1 via MFMA: per s-step, tiles 2s/2s+1 give h for j=0..3 / j=4..7.
#define GEMM_CHUNK(acc, XF, W1Fp, W2p, B2p)                                    \
    {                                                                          \
        _Pragma("unroll")                                                      \
        for (int t = 0; t < 8; ++t) {                                          \
            float b2n = (B2p)[t * 16 + col];                                   \
            floatx4 bi = (floatx4){b2n, b2n, b2n, b2n};                        \
            _Pragma("unroll")                                                  \
            for (int mt = 0; mt < 2; ++mt) acc[t][mt] = bi;                    \
        }                                                                      \
        const floatx4 zf = (floatx4){0.f, 0.f, 0.f, 0.f};                      \
        _Pragma("unroll")                                                      \
        for (int s = 0; s < 4; ++s) {                                          \
            bf16x8 a0 = (W1Fp)[(2 * s) * 64 + lane];                           \
            bf16x8 a1 = (W1Fp)[(2 * s + 1) * 64 + lane];                       \
            intx4 af[2];                                                       \
            _Pragma("unroll")                                                  \
            for (int mt = 0; mt < 2; ++mt) {                                   \
                floatx4 td0 = __builtin_amdgcn_mfma_f32_16x16x32_bf16(         \
                    a0, __builtin_bit_cast(bf16x8, (XF)[mt]), zf, 0, 0, 0);    \
                floatx4 td1 = __builtin_amdgcn_mfma_f32_16x16x32_bf16(         \
                    a1, __builtin_bit_cast(bf16x8, (XF)[mt]), zf, 0, 0, 0);    \
                af[mt][0] = pack2bf(fmaxf(td0[0], 0.f), fmaxf(td0[1], 0.f));   \
                af[mt][1] = pack2bf(fmaxf(td0[2], 0.f), fmaxf(td0[3], 0.f));   \
                af[mt][2] = pack2bf(fmaxf(td1[0], 0.f), fmaxf(td1[1], 0.f));   \
                af[mt][3] = pack2bf(fmaxf(td1[2], 0.f), fmaxf(td1[3], 0.f));   \
            }                                                                  \
            _Pragma("unroll")                                                  \
            for (int t = 0; t < 8; ++t) {                                      \
                bf16x8 bfr = (W2p)[(s * 8 + t) * 64 + lane];                   \
                _Pragma("unroll")                                              \
                for (int mt = 0; mt < 2; ++mt)                                 \
                    acc[t][mt] = __builtin_amdgcn_mfma_f32_16x16x32_bf16(      \
                        __builtin_bit_cast(bf16x8, af[mt]), bfr,               \
                        acc[t][mt], 0, 0, 0);                                  \
            }                                                                  \
        }                                                                      \
    }

// Build the layer-1 B-fragment for one x sample pair (hi/lo split):
// dwords {pack(xhi0,xhi1), same, pack(xlo0,xlo1), {1.0bf,1.0bf}}
static __device__ __forceinline__ intx4 make_xfrag(float2 xx) {
    int d0 = pack2bf(xx.x, xx.y);
    float r0 = __builtin_bit_cast(float, d0 << 16);
    float r1 = __builtin_bit_cast(float, d0 & 0xffff0000);
    int d2 = pack2bf(xx.x - r0, xx.y - r1);
    return (intx4){d0, d0, d2, 0x3f803f80};
}

// ---------------------------------------------------------------------------
// 512 blocks x 512 threads (8 waves). Per block (512 samples):
//   xa loads + small weights + pack W2a -> sync -> phase a (s_a -> LDS)
//   xb loads -> sync -> repack W2b -> sync -> phase b (t_j, softmax, store)
// ---------------------------------------------------------------------------
__global__ __launch_bounds__(512, 4)
void krone_fused(const float* __restrict__ x,
                 const float* __restrict__ w1a, const float* __restrict__ w1b,
                 const float* __restrict__ b1a, const float* __restrict__ b1b,
                 const float* __restrict__ w2a, const float* __restrict__ w2b,
                 const float* __restrict__ b2a, const float* __restrict__ b2b,
                 const float* __restrict__ w3a, const float* __restrict__ w3b,
                 const float* __restrict__ b3a, const float* __restrict__ b3b,
                 float* __restrict__ out) {
    __shared__ __align__(16) unsigned char smem[LDS_TOTAL];

    const int tid  = threadIdx.x;
    const int lane = tid & 63;
    const int wave = tid >> 6;
    const int quad = lane >> 4;
    const int col  = lane & 15;
    const int wbase = blockIdx.x * 512 + wave * 64;

    const bf16x8* W2   = (const bf16x8*)(smem + OFF_W2);
    const bf16x8* W1FA = (const bf16x8*)(smem + OFF_W1FA);
    const bf16x8* W1FB = (const bf16x8*)(smem + OFF_W1FB);
    const float*  B2A  = (const float*)(smem + OFF_B2A);
    const float*  B2B  = (const float*)(smem + OFF_B2B);
    const float*  W3A  = (const float*)(smem + OFF_W3A);
    const floatx4* W3T = (const floatx4*)(smem + OFF_W3T);
    float*        SA   = (float*)(smem + OFF_SA);
    const float2* xA = (const float2*)x;
    const float2* xB = xA + BTOT;

    const float b3a_ = b3a[0];
    const float b30 = b3b[0], b31 = b3b[1], b32 = b3b[2];

    // ---- stage: x(a) loads + all small weights + W2a pack ----
    float2 xv[4];   // [c*2+mt]
    #pragma unroll
    for (int c = 0; c < 2; ++c)
        #pragma unroll
        for (int mt = 0; mt < 2; ++mt)
            xv[c * 2 + mt] = xA[wbase + c * 32 + mt * 16 + col];

    pack_w2(smem + OFF_W2, tid, w2a);
    stage_w1f(smem, OFF_W1FA, tid, w1a, b1a);
    stage_w1f(smem, OFF_W1FB, tid, w1b, b1b);
    if (tid < 128) {
        ((float*)(smem + OFF_B2A))[tid] = b2a[tid];
        ((float*)(smem + OFF_B2B))[tid] = b2b[tid];
        ((float*)(smem + OFF_W3A))[tid] = w3a[tid];
    }
    if (tid < 384) {                                  // transpose w3b [3][128]
        int j = tid >> 7, n = tid & 127;              //  -> [128][4]
        ((float*)(smem + OFF_W3T))[n * 4 + j] = w3b[tid];
    }
    __syncthreads();

    // ---- phase a ----
    #pragma unroll
    for (int c = 0; c < 2; ++c) {
        __builtin_amdgcn_sched_barrier(0);
        intx4 xf[2];
        #pragma unroll
        for (int mt = 0; mt < 2; ++mt) xf[mt] = make_xfrag(xv[c * 2 + mt]);
        floatx4 acc[8][2];
        GEMM_CHUNK(acc, xf, W1FA, W2, B2A);
        __builtin_amdgcn_sched_barrier(0);

        float pa[2][4] = {};
        #pragma unroll
        for (int t = 0; t < 8; ++t) {
            float w3n = W3A[t * 16 + col];
            #pragma unroll
            for (int mt = 0; mt < 2; ++mt)
                #pragma unroll
                for (int r = 0; r < 4; ++r)
                    pa[mt][r] = fmaf(w3n, fmaxf(acc[t][mt][r], 0.f), pa[mt][r]);
        }
        #pragma unroll
        for (int mt = 0; mt < 2; ++mt) {
            float w = red4(pa[mt][0], pa[mt][1], pa[mt][2], pa[mt][3], col);
            if (col < 4) {
                int sl = mt * 16 + quad * 4 + col;
                SA[wave * 64 + c * 32 + sl] = (w + b3a_) * 1.44269504089f;
            }
        }
        __builtin_amdgcn_sched_barrier(0);
    }

    // ---- phase b transition: xB loads first (hide HBM latency under
    //      the barrier + W2 repack), then repack ----
    #pragma unroll
    for (int c = 0; c < 2; ++c)
        #pragma unroll
        for (int mt = 0; mt < 2; ++mt)
            xv[c * 2 + mt] = xB[wbase + c * 32 + mt * 16 + col];

    __syncthreads();   // everyone done reading W2a
    pack_w2(smem + OFF_W2, tid, w2b);
    __syncthreads();

    // ---- phase b ----
    #pragma unroll
    for (int c = 0; c < 2; ++c) {
        __builtin_amdgcn_sched_barrier(0);
        intx4 xf[2];
        #pragma unroll
        for (int mt = 0; mt < 2; ++mt) xf[mt] = make_xfrag(xv[c * 2 + mt]);
        floatx4 acc[8][2];
        GEMM_CHUNK(acc, xf, W1FB, W2, B2B);
        __builtin_amdgcn_sched_barrier(0);

        #pragma unroll
        for (int mt = 0; mt < 2; ++mt) {     // per-mt: 12 live partials
            float p0[4] = {}, p1[4] = {}, p2[4] = {};
            #pragma unroll
            for (int t = 0; t < 8; ++t) {
                floatx4 w3v = W3T[t * 16 + col];   // {w30,w31,w32,-}
                #pragma unroll
                for (int r = 0; r < 4; ++r) {
                    float h = fmaxf(acc[t][mt][r], 0.f);
                    p0[r] = fmaf(w3v.x, h, p0[r]);
                    p1[r] = fmaf(w3v.y, h, p1[r]);
                    p2[r] = fmaf(w3v.z, h, p2[r]);
                }
            }
            float t0 = red4(p0[0], p0[1], p0[2], p0[3], col) + b30;
            float t1 = red4(p1[0], p1[1], p1[2], p1[3], col) + b31;
            float t2 = red4(p2[0], p2[1], p2[2], p2[3], col) + b32;
            if (col < 4) {
                int sl = mt * 16 + quad * 4 + col;   // red4: lane col holds
                float sa = SA[wave * 64 + c * 32 + sl];  // sample col&3
                float y0 = sa * t0, y1 = sa * t1, y2 = sa * t2;
                float m = fmaxf(y0, fmaxf(y1, y2));
                float e0 = exp2f(y0 - m), e1 = exp2f(y1 - m), e2 = exp2f(y2 - m);
                float rs = __builtin_amdgcn_rcpf(e0 + e1 + e2);
                long o = (long)(wbase + c * 32 + sl) * 3;
                out[o]     = e0 * rs;
                out[o + 1] = e1 * rs;
                out[o + 2] = e2 * rs;
            }
        }
        __builtin_amdgcn_sched_barrier(0);
    }
}

extern "C" void kernel_launch(void* const* d_in, const int* in_sizes, int n_in,
                              void* d_out, int out_size, void* d_ws, size_t ws_size,
                              hipStream_t stream) {
    const float* x   = (const float*)d_in[0];
    const float* w1a = (const float*)d_in[1];
    const float* w1b = (const float*)d_in[2];
    const float* b1a = (const float*)d_in[3];
    const float* b1b = (const float*)d_in[4];
    const float* w2a = (const float*)d_in[5];
    const float* w2b = (const float*)d_in[6];
    const float* b2a = (const float*)d_in[7];
    const float* b2b = (const float*)d_in[8];
    const float* w3a = (const float*)d_in[9];
    const float* w3b = (const float*)d_in[10];
    const float* b3a = (const float*)d_in[11];
    const float* b3b = (const float*)d_in[12];
    float* out = (float*)d_out;

    krone_fused<<<NBLK, 512, 0, stream>>>(x, w1a, w1b, b1a, b1b, w2a, w2b,
                                          b2a, b2b, w3a, w3b, b3a, b3b, out);
}